// Round 4
// baseline (240.047 us; speedup 1.0000x reference)
//
#include <hip/hip_runtime.h>
#include <math.h>

// KDE log-density: out[i] = log(1e-8 + (1/N) * sum_j exp(t1 - 50*||xe_i - xb_j||^2))
// N = 16384, D = 16, fp32 in/out.
//
// Round 4: same MFMA + tile-screen algorithm as round 3 (one
// mfma_f32_32x32x16_bf16 per 32x32 tile, C-operand carries pe, inputs
// pre-scaled by sqrt(100*log2e) so d = 144.2695*dot + pe; tile skipped unless
// some d > THR - pb, i.e. some term could exceed 2^-135 — dropped terms shift
// the output < 1e-37). Changes:
//  - drop redundant hipMemsetAsync (kde_pre zeroes S)
//  - fuse the log-finalize into kde_main via last-block ticket (2 dispatches)
//  - peel prefetch epilogue, pointer-strength-reduced loop, max3-shaped tree

#define KDE_N 16384
#define KDE_D 16
#define MT 32                  // rows per wave m-tile
#define MWAVES 4               // waves per block
#define MB (MT * MWAVES)       // 128 eval rows per block
#define JSPLIT 16
#define JTILES (KDE_N / 32 / JSPLIT)        // 32 j-tiles per wave
#define NBLOCKS ((KDE_N / MB) * JSPLIT)     // 2048 blocks in kde_main
#define THR (-135.0f)          // log2-domain underflow screen

typedef __attribute__((ext_vector_type(8)))  short   short8;
typedef __attribute__((ext_vector_type(16))) float   float16_t;

__device__ __forceinline__ unsigned short f32_to_bf16_rne(float f) {
    unsigned int u = __float_as_uint(f);
    unsigned int r = (u + 0x7FFFu + ((u >> 16) & 1u)) >> 16;
    return (unsigned short)r;
}

// ---- prologue: pe / (THR - pb) precompute, scaled bf16 casts, zero S+ctr ----
__global__ void kde_pre(const float* __restrict__ xe, const float* __restrict__ xb,
                        float* __restrict__ S, float* __restrict__ pe,
                        float* __restrict__ pbthr, unsigned short* __restrict__ xe16,
                        unsigned short* __restrict__ xb16, int* __restrict__ ctr)
{
    const int t = blockIdx.x * blockDim.x + threadIdx.x;   // 0..32767
    const int row = t & (KDE_N - 1);
    const bool isB = t >= KDE_N;
    const float* src = (isB ? xb : xe) + (size_t)row * KDE_D;
    const float4* s4 = (const float4*)src;
    const float SQSC = 12.011224664550577f;   // sqrt(100*log2e)
    float q = 0.f;
    unsigned int w[8];
    #pragma unroll
    for (int k = 0; k < 4; ++k) {
        float4 v = s4[k];
        q += v.x*v.x + v.y*v.y + v.z*v.z + v.w*v.w;
        w[2*k+0] = (unsigned int)f32_to_bf16_rne(v.x * SQSC)
                 | ((unsigned int)f32_to_bf16_rne(v.y * SQSC) << 16);
        w[2*k+1] = (unsigned int)f32_to_bf16_rne(v.z * SQSC)
                 | ((unsigned int)f32_to_bf16_rne(v.w * SQSC) << 16);
    }
    unsigned short* dst = (isB ? xb16 : xe16) + (size_t)row * KDE_D;
    uint4* d4 = (uint4*)dst;
    d4[0] = make_uint4(w[0], w[1], w[2], w[3]);
    d4[1] = make_uint4(w[4], w[5], w[6], w[7]);
    const float T1L2E = -17.8920067984f;       // log2e * t1
    const float C72   = 72.134752044447963f;   // 50 * log2e
    if (!isB) { pe[row] = T1L2E - C72 * q; S[row] = 0.f; }
    else      { pbthr[row] = THR + C72 * q; }  // THR - pb,  pb = -C72*b2
    if (t == 0) *ctr = 0;
}

// ---- main: MFMA + max-screen; rare exp path; last block finalizes out ----
__global__ __launch_bounds__(256, 8) void kde_main(
    const unsigned short* __restrict__ xe16, const unsigned short* __restrict__ xb16,
    const float* __restrict__ pe, const float* __restrict__ pbthr,
    float* __restrict__ S, float* __restrict__ out, int* __restrict__ ctr)
{
    const int lane = threadIdx.x & 63;
    const int wave = threadIdx.x >> 6;
    const int m0   = blockIdx.x * MB + wave * MT;
    const int jt0  = blockIdx.y * JTILES;

    const int col  = lane & 31;   // A row / B col / C col
    const int half = lane >> 5;   // k-half for A/B frags; row-group for C

    // A fragment, loaded once (K=16 == D)
    const short8 af = *(const short8*)(xe16 + (size_t)(m0 + col) * KDE_D + half * 8);

    // C operand = pe for the 16 C rows this lane owns: row = (r&3)+8*(r>>2)+4*half
    float16_t perv;
    #pragma unroll
    for (int r = 0; r < 16; ++r)
        perv[r] = pe[m0 + (r & 3) + 8 * (r >> 2) + 4 * half];

    auto screen = [&](const float16_t& d, float thrv) {
        // max over this lane's 16 values, max3-friendly shape (8 ops)
        float m1 = fmaxf(fmaxf(d[0],  d[1]),  d[2]);
        float m2 = fmaxf(fmaxf(d[3],  d[4]),  d[5]);
        float m3 = fmaxf(fmaxf(d[6],  d[7]),  d[8]);
        float m4 = fmaxf(fmaxf(d[9],  d[10]), d[11]);
        float m5 = fmaxf(fmaxf(d[12], d[13]), d[14]);
        float x  = fmaxf(fmaxf(m1, m2), m3);
        float y  = fmaxf(fmaxf(m4, m5), d[15]);
        float mx = fmaxf(x, y);
        if (__any(mx > thrv)) {
            const float pbv = THR - thrv;
            #pragma unroll
            for (int r = 0; r < 16; ++r) {
                float e = exp2f(d[r] + pbv);
                if (e != 0.f)
                    atomicAdd(&S[m0 + (r & 3) + 8 * (r >> 2) + 4 * half], e);
            }
        }
    };

    const unsigned short* bp = xb16 + (size_t)(jt0 * 32 + col) * KDE_D + half * 8;
    const float*          tp = pbthr + (jt0 * 32 + col);
    short8 bf   = *(const short8*)bp;
    float  thrv = *tp;

    for (int t = 0; t < JTILES - 1; ++t) {
        bp += 32 * KDE_D;  tp += 32;
        const short8 bf_n  = *(const short8*)bp;
        const float  thr_n = *tp;
        float16_t d = __builtin_amdgcn_mfma_f32_32x32x16_bf16(af, bf, perv, 0, 0, 0);
        screen(d, thrv);
        bf = bf_n; thrv = thr_n;
    }
    {   // peeled last tile (no prefetch)
        float16_t d = __builtin_amdgcn_mfma_f32_32x32x16_bf16(af, bf, perv, 0, 0, 0);
        screen(d, thrv);
    }

    // ---- last-block finalization: out[i] = log(1e-8 + S[i]/N) ----
    __threadfence();               // block's atomicAdds complete & visible
    __syncthreads();
    __shared__ int isLast;
    if (threadIdx.x == 0) {
        int t = __hip_atomic_fetch_add(ctr, 1, __ATOMIC_ACQ_REL, __HIP_MEMORY_SCOPE_AGENT);
        isLast = (t == NBLOCKS - 1);
    }
    __syncthreads();
    if (isLast) {
        __threadfence();
        const float INVN = 1.0f / (float)KDE_N;
        for (int i = threadIdx.x; i < KDE_N; i += 256) {
            float s = __hip_atomic_load(&S[i], __ATOMIC_RELAXED, __HIP_MEMORY_SCOPE_AGENT);
            out[i] = logf(1e-8f + s * INVN);
        }
    }
}

extern "C" void kernel_launch(void* const* d_in, const int* in_sizes, int n_in,
                              void* d_out, int out_size, void* d_ws, size_t ws_size,
                              hipStream_t stream)
{
    const float* xe = (const float*)d_in[0];  // x_eval [16384,16] fp32
    const float* xb = (const float*)d_in[1];  // x_base [16384,16] fp32
    float* out = (float*)d_out;

    // ws layout: S[16384] | pe[16384] | pbthr[16384] | ctr(+pad 16B) | xe16 | xb16
    float* S     = (float*)d_ws;
    float* pe    = S + KDE_N;
    float* pbthr = pe + KDE_N;
    int*   ctr   = (int*)(pbthr + KDE_N);
    unsigned short* xe16 = (unsigned short*)(pbthr + KDE_N + 4);  // keep 16B align
    unsigned short* xb16 = xe16 + (size_t)KDE_N * KDE_D;

    kde_pre<<<(2 * KDE_N) / 256, 256, 0, stream>>>(xe, xb, S, pe, pbthr, xe16, xb16, ctr);
    dim3 grid(KDE_N / MB, JSPLIT);   // (128, 16) = 2048 blocks
    kde_main<<<grid, MWAVES * 64, 0, stream>>>(xe16, xb16, pe, pbthr, S, out, ctr);
}

// Round 5
// 69.291 us; speedup vs baseline: 3.4643x; 3.4643x over previous
//
#include <hip/hip_runtime.h>
#include <math.h>

// KDE log-density: out[i] = log(1e-8 + (1/N) * sum_j exp(t1 - 50*||xe_i - xb_j||^2))
// N = 16384, D = 16, fp32 in/out.
//
// Round 5: round-3 MFMA + tile-screen core (one mfma_f32_32x32x16_bf16 per
// 32x32 tile, C-operand carries pe, inputs pre-scaled by sqrt(100*log2e) so
// d = 144.2695*dot + pe; tile skipped unless some d > THR - pb — dropped
// terms shift the output < 1e-37).
//
// Round-4 post-mortem: last-block fusion via __threadfence + agent-scope
// acq_rel ticket cost ~150 us (2048 serialized L2-writeback/invalidate ops;
// kde_main VALUBusy fell to 4%). REVERTED — no device-scope fences anywhere.
//
// kde_final is instead eliminated by monotonicity: kde_pre pre-writes
// out[i] = log(1e-8) (correct when S[i]==0, i.e. ~all rows); the rare hit
// path computes cand = log(1e-8 + (old+e)/N) from atomicAdd's return and
// atomicMin's the raw bits into out (all values negative => float-max ==
// uint-min). The globally-last adder produces the exact final value.

#define KDE_N 16384
#define KDE_D 16
#define MT 32                  // rows per wave m-tile
#define MWAVES 4               // waves per block
#define MB (MT * MWAVES)       // 128 eval rows per block
#define JSPLIT 16
#define JTILES (KDE_N / 32 / JSPLIT)   // 32 j-tiles per wave
#define THR (-135.0f)          // log2-domain underflow screen

typedef __attribute__((ext_vector_type(8)))  short   short8;
typedef __attribute__((ext_vector_type(16))) float   float16_t;

__device__ __forceinline__ unsigned short f32_to_bf16_rne(float f) {
    unsigned int u = __float_as_uint(f);
    unsigned int r = (u + 0x7FFFu + ((u >> 16) & 1u)) >> 16;
    return (unsigned short)r;
}

// ---- prologue: pe / (THR - pb), scaled bf16 casts, zero S, default out ----
__global__ void kde_pre(const float* __restrict__ xe, const float* __restrict__ xb,
                        float* __restrict__ S, float* __restrict__ pe,
                        float* __restrict__ pbthr, unsigned short* __restrict__ xe16,
                        unsigned short* __restrict__ xb16, float* __restrict__ out)
{
    const int t = blockIdx.x * blockDim.x + threadIdx.x;   // 0..32767
    const int row = t & (KDE_N - 1);
    const bool isB = t >= KDE_N;
    const float* src = (isB ? xb : xe) + (size_t)row * KDE_D;
    const float4* s4 = (const float4*)src;
    const float SQSC = 12.011224664550577f;   // sqrt(100*log2e)
    float q = 0.f;
    unsigned int w[8];
    #pragma unroll
    for (int k = 0; k < 4; ++k) {
        float4 v = s4[k];
        q += v.x*v.x + v.y*v.y + v.z*v.z + v.w*v.w;
        w[2*k+0] = (unsigned int)f32_to_bf16_rne(v.x * SQSC)
                 | ((unsigned int)f32_to_bf16_rne(v.y * SQSC) << 16);
        w[2*k+1] = (unsigned int)f32_to_bf16_rne(v.z * SQSC)
                 | ((unsigned int)f32_to_bf16_rne(v.w * SQSC) << 16);
    }
    unsigned short* dst = (isB ? xb16 : xe16) + (size_t)row * KDE_D;
    uint4* d4 = (uint4*)dst;
    d4[0] = make_uint4(w[0], w[1], w[2], w[3]);
    d4[1] = make_uint4(w[4], w[5], w[6], w[7]);
    const float T1L2E  = -17.8920067984f;       // log2e * t1
    const float C72    = 72.134752044447963f;   // 50 * log2e
    const float LOG1EM8 = -18.420680743952367f; // log(1e-8)
    if (!isB) { pe[row] = T1L2E - C72 * q; S[row] = 0.f; out[row] = LOG1EM8; }
    else      { pbthr[row] = THR + C72 * q; }   // THR - pb,  pb = -C72*b2
}

// ---- main: MFMA + max-screen; rare exp path updates S and out directly ----
__global__ __launch_bounds__(256, 8) void kde_main(
    const unsigned short* __restrict__ xe16, const unsigned short* __restrict__ xb16,
    const float* __restrict__ pe, const float* __restrict__ pbthr,
    float* __restrict__ S, float* __restrict__ out)
{
    const int lane = threadIdx.x & 63;
    const int wave = threadIdx.x >> 6;
    const int m0   = blockIdx.x * MB + wave * MT;
    const int jt0  = blockIdx.y * JTILES;

    const int col  = lane & 31;   // A row / B col / C col
    const int half = lane >> 5;   // k-half for A/B frags; row-group for C

    // A fragment, loaded once (K=16 == D)
    const short8 af = *(const short8*)(xe16 + (size_t)(m0 + col) * KDE_D + half * 8);

    // C operand = pe for the 16 C rows this lane owns: row = (r&3)+8*(r>>2)+4*half
    float16_t perv;
    #pragma unroll
    for (int r = 0; r < 16; ++r)
        perv[r] = pe[m0 + (r & 3) + 8 * (r >> 2) + 4 * half];

    const float INVN = 1.0f / (float)KDE_N;

    auto screen = [&](const float16_t& d, float thrv) {
        // max over this lane's 16 values, max3-friendly shape
        float m1 = fmaxf(fmaxf(d[0],  d[1]),  d[2]);
        float m2 = fmaxf(fmaxf(d[3],  d[4]),  d[5]);
        float m3 = fmaxf(fmaxf(d[6],  d[7]),  d[8]);
        float m4 = fmaxf(fmaxf(d[9],  d[10]), d[11]);
        float m5 = fmaxf(fmaxf(d[12], d[13]), d[14]);
        float x  = fmaxf(fmaxf(m1, m2), m3);
        float y  = fmaxf(fmaxf(m4, m5), d[15]);
        float mx = fmaxf(x, y);
        if (__any(mx > thrv)) {
            // rare: some term may exceed 2^-135
            const float pbv = THR - thrv;
            #pragma unroll
            for (int r = 0; r < 16; ++r) {
                float e = exp2f(d[r] + pbv);
                if (e != 0.f) {
                    const int row = m0 + (r & 3) + 8 * (r >> 2) + 4 * half;
                    float old  = atomicAdd(&S[row], e);
                    float cand = logf(1e-8f + (old + e) * INVN);
                    // all cands negative: float-max == uint-min on raw bits
                    atomicMin((unsigned int*)&out[row], __float_as_uint(cand));
                }
            }
        }
    };

    const unsigned short* bp = xb16 + (size_t)(jt0 * 32 + col) * KDE_D + half * 8;
    const float*          tp = pbthr + (jt0 * 32 + col);
    short8 bf   = *(const short8*)bp;
    float  thrv = *tp;

    #pragma unroll 4
    for (int t = 0; t < JTILES - 1; ++t) {
        bp += 32 * KDE_D;  tp += 32;
        const short8 bf_n  = *(const short8*)bp;
        const float  thr_n = *tp;
        float16_t d = __builtin_amdgcn_mfma_f32_32x32x16_bf16(af, bf, perv, 0, 0, 0);
        screen(d, thrv);
        bf = bf_n; thrv = thr_n;
    }
    {   // peeled last tile (no prefetch)
        float16_t d = __builtin_amdgcn_mfma_f32_32x32x16_bf16(af, bf, perv, 0, 0, 0);
        screen(d, thrv);
    }
}

extern "C" void kernel_launch(void* const* d_in, const int* in_sizes, int n_in,
                              void* d_out, int out_size, void* d_ws, size_t ws_size,
                              hipStream_t stream)
{
    const float* xe = (const float*)d_in[0];  // x_eval [16384,16] fp32
    const float* xb = (const float*)d_in[1];  // x_base [16384,16] fp32
    float* out = (float*)d_out;

    // ws layout: S[16384] | pe[16384] | pbthr[16384] | xe16 | xb16
    float* S     = (float*)d_ws;
    float* pe    = S + KDE_N;
    float* pbthr = pe + KDE_N;
    unsigned short* xe16 = (unsigned short*)(pbthr + KDE_N);
    unsigned short* xb16 = xe16 + (size_t)KDE_N * KDE_D;

    kde_pre<<<(2 * KDE_N) / 256, 256, 0, stream>>>(xe, xb, S, pe, pbthr, xe16, xb16, out);
    dim3 grid(KDE_N / MB, JSPLIT);   // (128, 16) = 2048 blocks
    kde_main<<<grid, MWAVES * 64, 0, stream>>>(xe16, xb16, pe, pbthr, S, out);
}